// Round 1
// baseline (7920.119 us; speedup 1.0000x reference)
//
#include <hip/hip_runtime.h>
#include <hip/hip_bf16.h>

#define DIM 48

// deg[i] = 1.0 (self loop)
__global__ void k_init_deg(float* deg, int n) {
    int i = blockIdx.x * blockDim.x + threadIdx.x;
    if (i < n) deg[i] = 1.0f;
}

// deg[col[e]] += 1
__global__ void k_count_deg(const int* __restrict__ col, float* deg, int E) {
    int i = blockIdx.x * blockDim.x + threadIdx.x;
    int stride = gridDim.x * blockDim.x;
    for (; i < E; i += stride) atomicAdd(&deg[col[i]], 1.0f);
}

// dinv = rsqrt(deg), also zero g[0..63]
__global__ void k_finish_dinv(float* dinv, int n, float* g) {
    int i = blockIdx.x * blockDim.x + threadIdx.x;
    if (i < n) dinv[i] = 1.0f / sqrtf(dinv[i]);
    if (i < 64) g[i] = 0.0f;
}

// hs[i,:] = (in[i,:] @ W) * dinv[i]; acc[i,:] = hs[i,:]  (self-loop init)
// NOTE: may be called with acc == in (per-thread row ownership; full row is
// read into registers before any write), so no __restrict__ on in/acc.
__global__ void k_mm_scale(const float* in, const float* __restrict__ W,
                           const float* __restrict__ dinv,
                           float* __restrict__ hs, float* acc, int n) {
    __shared__ float Ws[DIM * DIM];
    for (int i = threadIdx.x; i < DIM * DIM; i += blockDim.x) Ws[i] = W[i];
    __syncthreads();
    int node = blockIdx.x * blockDim.x + threadIdx.x;
    int stride = gridDim.x * blockDim.x;
    for (; node < n; node += stride) {
        float xr[DIM];
        const float4* xp = (const float4*)(in + (size_t)node * DIM);
        #pragma unroll
        for (int j = 0; j < DIM / 4; ++j) {
            float4 v = xp[j];
            xr[j * 4 + 0] = v.x; xr[j * 4 + 1] = v.y;
            xr[j * 4 + 2] = v.z; xr[j * 4 + 3] = v.w;
        }
        float o[DIM];
        #pragma unroll
        for (int f = 0; f < DIM; ++f) o[f] = 0.0f;
        for (int k = 0; k < DIM; ++k) {
            float xv = xr[k];
            #pragma unroll
            for (int f = 0; f < DIM; ++f) o[f] = fmaf(xv, Ws[k * DIM + f], o[f]);
        }
        float d = dinv[node];
        float4* hp = (float4*)(hs + (size_t)node * DIM);
        float4* ap = (float4*)(acc + (size_t)node * DIM);
        #pragma unroll
        for (int j = 0; j < DIM / 4; ++j) {
            float4 v = make_float4(o[j * 4 + 0] * d, o[j * 4 + 1] * d,
                                   o[j * 4 + 2] * d, o[j * 4 + 3] * d);
            hp[j] = v;
            ap[j] = v;
        }
    }
}

// For each edge e and float4 chunk c: acc[col[e], 4c..4c+3] += hs[row[e], 4c..4c+3]
__global__ void k_scatter(const int* __restrict__ row, const int* __restrict__ col,
                          const float* __restrict__ hs, float* acc, int E) {
    int idx = blockIdx.x * blockDim.x + threadIdx.x;
    int stride = gridDim.x * blockDim.x;
    int total = E * (DIM / 4);
    for (; idx < total; idx += stride) {
        int c = idx / E;          // chunk 0..11 (consecutive threads: same c)
        int e = idx - c * E;      // coalesced row/col loads
        int r = row[e];
        int t = col[e];
        float4 v = *(const float4*)(hs + (size_t)r * DIM + c * 4);
        float* dst = acc + (size_t)t * DIM + c * 4;
        atomicAdd(dst + 0, v.x);
        atomicAdd(dst + 1, v.y);
        atomicAdd(dst + 2, v.z);
        atomicAdd(dst + 3, v.w);
    }
}

// out[i,f] = leaky_relu(acc[i,f] * dinv[i] + b[f], 0.01)
__global__ void k_act(const float* __restrict__ acc, const float* __restrict__ dinv,
                      const float* __restrict__ b, float* __restrict__ out, int n) {
    int idx = blockIdx.x * blockDim.x + threadIdx.x;
    int stride = gridDim.x * blockDim.x;
    int total = n * DIM;
    for (; idx < total; idx += stride) {
        int i = idx / DIM;
        int f = idx - i * DIM;
        float v = acc[idx] * dinv[i] + b[f];
        out[idx] = (v >= 0.0f) ? v : 0.01f * v;
    }
}

// g[f] += sum_i acc[i,f] * dinv[i]   (block-partial, then atomic)
__global__ void k_reduce(const float* __restrict__ acc, const float* __restrict__ dinv,
                         float* g, int n) {
    __shared__ float sm[192];
    int f = threadIdx.x % DIM;
    int r = threadIdx.x / DIM;   // 0..3
    float s = 0.0f;
    for (int i = blockIdx.x * 4 + r; i < n; i += gridDim.x * 4) {
        s += acc[(size_t)i * DIM + f] * dinv[i];
    }
    sm[threadIdx.x] = s;
    __syncthreads();
    if (threadIdx.x < DIM) {
        float tot = sm[f] + sm[DIM + f] + sm[2 * DIM + f] + sm[3 * DIM + f];
        atomicAdd(&g[f], tot);
    }
}

// out[k] = sum_f (g[f] + n*b2[f]) * Wlin[f,k] + blin[k]
__global__ void k_final(const float* __restrict__ g, const float* __restrict__ b2,
                        const float* __restrict__ Wlin, const float* __restrict__ blin,
                        float* __restrict__ out, int n) {
    int k = threadIdx.x;
    if (k < 2) {
        float s = blin[k];
        for (int f = 0; f < DIM; ++f)
            s += (g[f] + (float)n * b2[f]) * Wlin[f * 2 + k];
        out[k] = s;
    }
}

extern "C" void kernel_launch(void* const* d_in, const int* in_sizes, int n_in,
                              void* d_out, int out_size, void* d_ws, size_t ws_size,
                              hipStream_t stream) {
    const float* x    = (const float*)d_in[0];
    const int*   ei   = (const int*)d_in[1];
    const float* W1   = (const float*)d_in[2];
    const float* b1   = (const float*)d_in[3];
    const float* W2   = (const float*)d_in[4];
    const float* b2   = (const float*)d_in[5];
    const float* Wlin = (const float*)d_in[6];
    const float* blin = (const float*)d_in[7];
    float* out = (float*)d_out;

    int N = in_sizes[0] / DIM;
    int E = in_sizes[1] / 2;
    const int* row = ei;
    const int* col = ei + E;

    float* ws   = (float*)d_ws;
    float* dinv = ws;                        // N floats (deg -> dinv in place)
    float* g    = ws + N;                    // 64 floats
    float* buf1 = g + 64;                    // N*48
    float* buf2 = buf1 + (size_t)N * DIM;    // N*48

    int nblk = (N + 255) / 256;

    // degrees + dinv
    k_init_deg<<<nblk, 256, 0, stream>>>(dinv, N);
    k_count_deg<<<1024, 256, 0, stream>>>(col, dinv, E);
    k_finish_dinv<<<nblk, 256, 0, stream>>>(dinv, N, g);

    // layer 1: hs1 -> buf1, acc1 -> buf2
    k_mm_scale<<<1024, 256, 0, stream>>>(x, W1, dinv, buf1, buf2, N);
    k_scatter<<<2048, 256, 0, stream>>>(row, col, buf1, buf2, E);
    // h2in -> buf1
    k_act<<<2048, 256, 0, stream>>>(buf2, dinv, b1, buf1, N);

    // layer 2: hs2 -> buf2, acc2 -> buf1 (in-place with input, safe per-row)
    k_mm_scale<<<1024, 256, 0, stream>>>(buf1, W2, dinv, buf2, buf1, N);
    k_scatter<<<2048, 256, 0, stream>>>(row, col, buf2, buf1, E);

    // global pool + final linear
    k_reduce<<<1024, 192, 0, stream>>>(buf1, dinv, g, N);
    k_final<<<1, 64, 0, stream>>>(g, b2, Wlin, blin, out, N);
}

// Round 2
// 569.461 us; speedup vs baseline: 13.9081x; 13.9081x over previous
//
#include <hip/hip_runtime.h>
#include <hip/hip_bf16.h>

#define DIM 48
#define NPB 16   // nodes per gather block
#define TPN 12   // threads per node (float4 chunks)

// degi = 0, g = 0
__global__ void k_zero(int* __restrict__ degi, float* __restrict__ g, int n) {
    int i = blockIdx.x * blockDim.x + threadIdx.x;
    if (i < n) degi[i] = 0;
    if (i < 64) g[i] = 0.0f;
}

// in-degree histogram (int atomics)
__global__ void k_hist(const int* __restrict__ col, int* __restrict__ degi, int E) {
    int i = blockIdx.x * blockDim.x + threadIdx.x;
    int st = gridDim.x * blockDim.x;
    for (; i < E; i += st) atomicAdd(&degi[col[i]], 1);
}

// dinv[i] = 1/sqrt(indeg + 1)   (+1 = self loop)
__global__ void k_dinv(const int* __restrict__ degi, float* __restrict__ dinv, int n) {
    int i = blockIdx.x * blockDim.x + threadIdx.x;
    if (i < n) dinv[i] = 1.0f / sqrtf((float)(degi[i] + 1));
}

// single-block exclusive scan of degi[0..n) -> cursor[0..n)
__global__ void k_scan(const int* __restrict__ degi, int* __restrict__ cursor, int n) {
    __shared__ int part[1024];
    int t = threadIdx.x;
    int chunk = (n + 1023) >> 10;
    int lo = t * chunk;
    int hi = min(lo + chunk, n);
    int s = 0;
    for (int i = lo; i < hi; ++i) s += degi[i];
    part[t] = s;
    __syncthreads();
    for (int off = 1; off < 1024; off <<= 1) {
        int v = (t >= off) ? part[t - off] : 0;
        __syncthreads();
        part[t] += v;
        __syncthreads();
    }
    int run = (t == 0) ? 0 : part[t - 1];
    for (int i = lo; i < hi; ++i) { cursor[i] = run; run += degi[i]; }
}

// srcs[pos] = row, bucketed by col. Afterwards cursor[i] == end offset of node i.
__global__ void k_reorder(const int* __restrict__ row, const int* __restrict__ col,
                          int* cursor, int* __restrict__ srcs, int E) {
    int i = blockIdx.x * blockDim.x + threadIdx.x;
    int st = gridDim.x * blockDim.x;
    for (; i < E; i += st) {
        int p = atomicAdd(&cursor[col[i]], 1);
        srcs[p] = row[i];
    }
}

// hs[i,:] = (in[i,:] @ W) * dinv[i]
__global__ void k_mm_scale(const float* __restrict__ in, const float* __restrict__ W,
                           const float* __restrict__ dinv,
                           float* __restrict__ hs, int n) {
    __shared__ float Ws[DIM * DIM];
    for (int i = threadIdx.x; i < DIM * DIM; i += blockDim.x) Ws[i] = W[i];
    __syncthreads();
    int node = blockIdx.x * blockDim.x + threadIdx.x;
    if (node >= n) return;
    float xr[DIM];
    const float4* xp = (const float4*)(in + (size_t)node * DIM);
    #pragma unroll
    for (int j = 0; j < DIM / 4; ++j) {
        float4 v = xp[j];
        xr[j * 4 + 0] = v.x; xr[j * 4 + 1] = v.y;
        xr[j * 4 + 2] = v.z; xr[j * 4 + 3] = v.w;
    }
    float o[DIM];
    #pragma unroll
    for (int f = 0; f < DIM; ++f) o[f] = 0.0f;
    for (int k = 0; k < DIM; ++k) {
        float xv = xr[k];
        #pragma unroll
        for (int f = 0; f < DIM; ++f) o[f] = fmaf(xv, Ws[k * DIM + f], o[f]);
    }
    float d = dinv[node];
    float4* hp = (float4*)(hs + (size_t)node * DIM);
    #pragma unroll
    for (int j = 0; j < DIM / 4; ++j)
        hp[j] = make_float4(o[j * 4] * d, o[j * 4 + 1] * d, o[j * 4 + 2] * d, o[j * 4 + 3] * d);
}

// out[i,:] = act( dinv[i] * (hs[i,:] + sum_{src in-edges} hs[src,:]) [+ b] )
// RELU=1: add bias b and apply leaky_relu(0.01). RELU=0: no bias, no act.
template <int RELU>
__global__ void k_gather(const float* __restrict__ hs, const int* __restrict__ cursor,
                         const int* __restrict__ srcs, const float* __restrict__ dinv,
                         const float* __restrict__ b, float* __restrict__ out, int n) {
    int t = threadIdx.x;
    int local = t / TPN;
    int c = t - local * TPN;           // float4 chunk 0..11
    int i = blockIdx.x * NPB + local;
    if (i >= n) return;
    int start = (i == 0) ? 0 : cursor[i - 1];
    int end = cursor[i];
    float4 s = *(const float4*)(hs + (size_t)i * DIM + c * 4);   // self loop
    for (int j = start; j < end; ++j) {
        int src = srcs[j];
        float4 v = *(const float4*)(hs + (size_t)src * DIM + c * 4);
        s.x += v.x; s.y += v.y; s.z += v.z; s.w += v.w;
    }
    float d = dinv[i];
    if (RELU) {
        const float4 bb = *(const float4*)(b + c * 4);
        float4 r;
        r.x = s.x * d + bb.x; r.y = s.y * d + bb.y;
        r.z = s.z * d + bb.z; r.w = s.w * d + bb.w;
        r.x = (r.x >= 0.f) ? r.x : 0.01f * r.x;
        r.y = (r.y >= 0.f) ? r.y : 0.01f * r.y;
        r.z = (r.z >= 0.f) ? r.z : 0.01f * r.z;
        r.w = (r.w >= 0.f) ? r.w : 0.01f * r.w;
        *(float4*)(out + (size_t)i * DIM + c * 4) = r;
    } else {
        s.x *= d; s.y *= d; s.z *= d; s.w *= d;
        *(float4*)(out + (size_t)i * DIM + c * 4) = s;
    }
}

// g[f] += column sums of acc
__global__ void k_reduce(const float* __restrict__ acc, float* g, int n) {
    __shared__ float sm[192];
    int f = threadIdx.x % DIM;
    int r = threadIdx.x / DIM;   // 0..3
    float s = 0.0f;
    for (int i = blockIdx.x * 4 + r; i < n; i += gridDim.x * 4)
        s += acc[(size_t)i * DIM + f];
    sm[threadIdx.x] = s;
    __syncthreads();
    if (threadIdx.x < DIM)
        atomicAdd(&g[f], sm[f] + sm[DIM + f] + sm[2 * DIM + f] + sm[3 * DIM + f]);
}

// out[k] = sum_f (g[f] + n*b2[f]) * Wlin[f,k] + blin[k]
__global__ void k_final(const float* __restrict__ g, const float* __restrict__ b2,
                        const float* __restrict__ Wlin, const float* __restrict__ blin,
                        float* __restrict__ out, int n) {
    int k = threadIdx.x;
    if (k < 2) {
        float s = blin[k];
        for (int f = 0; f < DIM; ++f)
            s += (g[f] + (float)n * b2[f]) * Wlin[f * 2 + k];
        out[k] = s;
    }
}

extern "C" void kernel_launch(void* const* d_in, const int* in_sizes, int n_in,
                              void* d_out, int out_size, void* d_ws, size_t ws_size,
                              hipStream_t stream) {
    const float* x    = (const float*)d_in[0];
    const int*   ei   = (const int*)d_in[1];
    const float* W1   = (const float*)d_in[2];
    const float* b1   = (const float*)d_in[3];
    const float* W2   = (const float*)d_in[4];
    const float* b2   = (const float*)d_in[5];
    const float* Wlin = (const float*)d_in[6];
    const float* blin = (const float*)d_in[7];
    float* out = (float*)d_out;

    int N = in_sizes[0] / DIM;
    int E = in_sizes[1] / 2;
    const int* row = ei;
    const int* col = ei + E;

    // workspace layout
    int*   degi   = (int*)d_ws;                 // N
    int*   cursor = degi + N;                   // N
    int*   srcs   = cursor + N;                 // E
    float* dinv   = (float*)(srcs + E);         // N
    float* g      = dinv + N;                   // 64
    float* buf1   = g + 64;                     // N*DIM (16B-aligned for N=100k)
    float* buf2   = buf1 + (size_t)N * DIM;     // N*DIM

    int nblk = (N + 255) / 256;

    // CSR build (shared by both layers)
    k_zero<<<nblk, 256, 0, stream>>>(degi, g, N);
    k_hist<<<2048, 256, 0, stream>>>(col, degi, E);
    k_dinv<<<nblk, 256, 0, stream>>>(degi, dinv, N);
    k_scan<<<1, 1024, 0, stream>>>(degi, cursor, N);
    k_reorder<<<2048, 256, 0, stream>>>(row, col, cursor, srcs, E);

    int gblk = (N + NPB - 1) / NPB;

    // layer 1: hs1 -> buf1; h (post-bias+leaky) -> buf2
    k_mm_scale<<<nblk, 256, 0, stream>>>(x, W1, dinv, buf1, N);
    k_gather<1><<<gblk, NPB * TPN, 0, stream>>>(buf1, cursor, srcs, dinv, b1, buf2, N);

    // layer 2: hs2 -> buf1; h2 (pre-bias) -> buf2... (bias folded into k_final)
    k_mm_scale<<<nblk, 256, 0, stream>>>(buf2, W2, dinv, buf1, N);
    k_gather<0><<<gblk, NPB * TPN, 0, stream>>>(buf1, cursor, srcs, dinv, b2, buf2, N);

    // global pool + final linear
    k_reduce<<<1024, 192, 0, stream>>>(buf2, g, N);
    k_final<<<1, 64, 0, stream>>>(g, b2, Wlin, blin, out, N);
}

// Round 3
// 406.648 us; speedup vs baseline: 19.4766x; 1.4004x over previous
//
#include <hip/hip_runtime.h>
#include <hip/hip_bf16.h>

#define DIM 48
#define NPB 16   // nodes per gather block
#define TPN 12   // threads per node (float4 chunks)

#define SB 256            // scan block threads
#define SE 4              // elements per scan thread
#define SCHUNK (SB * SE)  // 1024 elements per scan block

// degi = 0, g = 0
__global__ void k_zero(int* __restrict__ degi, float* __restrict__ g, int n) {
    int i = blockIdx.x * blockDim.x + threadIdx.x;
    if (i < n) degi[i] = 0;
    if (i < 64) g[i] = 0.0f;
}

// in-degree histogram (int atomics)
__global__ void k_hist(const int* __restrict__ col, int* __restrict__ degi, int E) {
    int i = blockIdx.x * blockDim.x + threadIdx.x;
    int st = gridDim.x * blockDim.x;
    for (; i < E; i += st) atomicAdd(&degi[col[i]], 1);
}

// Block-level exclusive scan: cursor[i] = excl prefix within block,
// bsum[b] = block total. Also dinv[i] = rsqrt(degi[i]+1).
__global__ void k_scan_up(const int* __restrict__ degi, int* __restrict__ cursor,
                          float* __restrict__ dinv, int* __restrict__ bsum, int n) {
    __shared__ int sm[SB];
    int base = blockIdx.x * SCHUNK + threadIdx.x * SE;
    int v[SE];
    #pragma unroll
    for (int j = 0; j < SE; ++j) {
        int idx = base + j;
        v[j] = (idx < n) ? degi[idx] : 0;
    }
    int s = v[0] + v[1] + v[2] + v[3];
    sm[threadIdx.x] = s;
    __syncthreads();
    for (int off = 1; off < SB; off <<= 1) {
        int t = (threadIdx.x >= off) ? sm[threadIdx.x - off] : 0;
        __syncthreads();
        sm[threadIdx.x] += t;
        __syncthreads();
    }
    if (threadIdx.x == SB - 1) bsum[blockIdx.x] = sm[SB - 1];
    int run = (threadIdx.x == 0) ? 0 : sm[threadIdx.x - 1];
    #pragma unroll
    for (int j = 0; j < SE; ++j) {
        int idx = base + j;
        if (idx < n) {
            cursor[idx] = run;
            dinv[idx] = 1.0f / sqrtf((float)(v[j] + 1));
            run += v[j];
        }
    }
}

// exclusive scan of bsum[0..nb), nb <= 256, single block of 256
__global__ void k_scan_mid(int* bsum, int nb) {
    __shared__ int sm[256];
    int t = threadIdx.x;
    sm[t] = (t < nb) ? bsum[t] : 0;
    __syncthreads();
    for (int off = 1; off < 256; off <<= 1) {
        int v = (t >= off) ? sm[t - off] : 0;
        __syncthreads();
        sm[t] += v;
        __syncthreads();
    }
    if (t < nb) bsum[t] = (t == 0) ? 0 : sm[t - 1];
}

// cursor[i] += bsum[blockIdx]
__global__ void k_scan_down(int* cursor, const int* __restrict__ bsum, int n) {
    int off = bsum[blockIdx.x];
    int base = blockIdx.x * SCHUNK + threadIdx.x * SE;
    if (base + SE <= n) {
        int4* p = (int4*)(cursor + base);
        int4 x = *p;
        x.x += off; x.y += off; x.z += off; x.w += off;
        *p = x;
    } else {
        for (int j = 0; j < SE; ++j) {
            int idx = base + j;
            if (idx < n) cursor[idx] += off;
        }
    }
}

// srcs[pos] = row, bucketed by col. Afterwards cursor[i] == end offset of node i.
__global__ void k_reorder(const int* __restrict__ row, const int* __restrict__ col,
                          int* cursor, int* __restrict__ srcs, int E) {
    int i = blockIdx.x * blockDim.x + threadIdx.x;
    int st = gridDim.x * blockDim.x;
    for (; i < E; i += st) {
        int p = atomicAdd(&cursor[col[i]], 1);
        srcs[p] = row[i];
    }
}

// hs[i,:] = (in[i,:] @ W) * dinv[i]
__global__ void k_mm_scale(const float* __restrict__ in, const float* __restrict__ W,
                           const float* __restrict__ dinv,
                           float* __restrict__ hs, int n) {
    __shared__ float Ws[DIM * DIM];
    for (int i = threadIdx.x; i < DIM * DIM; i += blockDim.x) Ws[i] = W[i];
    __syncthreads();
    int node = blockIdx.x * blockDim.x + threadIdx.x;
    if (node >= n) return;
    float xr[DIM];
    const float4* xp = (const float4*)(in + (size_t)node * DIM);
    #pragma unroll
    for (int j = 0; j < DIM / 4; ++j) {
        float4 v = xp[j];
        xr[j * 4 + 0] = v.x; xr[j * 4 + 1] = v.y;
        xr[j * 4 + 2] = v.z; xr[j * 4 + 3] = v.w;
    }
    float o[DIM];
    #pragma unroll
    for (int f = 0; f < DIM; ++f) o[f] = 0.0f;
    for (int k = 0; k < DIM; ++k) {
        float xv = xr[k];
        #pragma unroll
        for (int f = 0; f < DIM; ++f) o[f] = fmaf(xv, Ws[k * DIM + f], o[f]);
    }
    float d = dinv[node];
    float4* hp = (float4*)(hs + (size_t)node * DIM);
    #pragma unroll
    for (int j = 0; j < DIM / 4; ++j)
        hp[j] = make_float4(o[j * 4] * d, o[j * 4 + 1] * d, o[j * 4 + 2] * d, o[j * 4 + 3] * d);
}

// out[i,:] = act( dinv[i] * (hs[i,:] + sum_{src in-edges} hs[src,:]) [+ b] )
template <int RELU>
__global__ void k_gather(const float* __restrict__ hs, const int* __restrict__ cursor,
                         const int* __restrict__ srcs, const float* __restrict__ dinv,
                         const float* __restrict__ b, float* __restrict__ out, int n) {
    int t = threadIdx.x;
    int local = t / TPN;
    int c = t - local * TPN;           // float4 chunk 0..11
    int i = blockIdx.x * NPB + local;
    if (i >= n) return;
    int start = (i == 0) ? 0 : cursor[i - 1];
    int end = cursor[i];
    float4 s = *(const float4*)(hs + (size_t)i * DIM + c * 4);   // self loop
    for (int j = start; j < end; ++j) {
        int src = srcs[j];
        float4 v = *(const float4*)(hs + (size_t)src * DIM + c * 4);
        s.x += v.x; s.y += v.y; s.z += v.z; s.w += v.w;
    }
    float d = dinv[i];
    if (RELU) {
        const float4 bb = *(const float4*)(b + c * 4);
        float4 r;
        r.x = s.x * d + bb.x; r.y = s.y * d + bb.y;
        r.z = s.z * d + bb.z; r.w = s.w * d + bb.w;
        r.x = (r.x >= 0.f) ? r.x : 0.01f * r.x;
        r.y = (r.y >= 0.f) ? r.y : 0.01f * r.y;
        r.z = (r.z >= 0.f) ? r.z : 0.01f * r.z;
        r.w = (r.w >= 0.f) ? r.w : 0.01f * r.w;
        *(float4*)(out + (size_t)i * DIM + c * 4) = r;
    } else {
        s.x *= d; s.y *= d; s.z *= d; s.w *= d;
        *(float4*)(out + (size_t)i * DIM + c * 4) = s;
    }
}

// g[f] += column sums of acc
__global__ void k_reduce(const float* __restrict__ acc, float* g, int n) {
    __shared__ float sm[192];
    int f = threadIdx.x % DIM;
    int r = threadIdx.x / DIM;   // 0..3
    float s = 0.0f;
    for (int i = blockIdx.x * 4 + r; i < n; i += gridDim.x * 4)
        s += acc[(size_t)i * DIM + f];
    sm[threadIdx.x] = s;
    __syncthreads();
    if (threadIdx.x < DIM)
        atomicAdd(&g[f], sm[f] + sm[DIM + f] + sm[2 * DIM + f] + sm[3 * DIM + f]);
}

// out[k] = sum_f (g[f] + n*b2[f]) * Wlin[f,k] + blin[k]
__global__ void k_final(const float* __restrict__ g, const float* __restrict__ b2,
                        const float* __restrict__ Wlin, const float* __restrict__ blin,
                        float* __restrict__ out, int n) {
    int k = threadIdx.x;
    if (k < 2) {
        float s = blin[k];
        for (int f = 0; f < DIM; ++f)
            s += (g[f] + (float)n * b2[f]) * Wlin[f * 2 + k];
        out[k] = s;
    }
}

extern "C" void kernel_launch(void* const* d_in, const int* in_sizes, int n_in,
                              void* d_out, int out_size, void* d_ws, size_t ws_size,
                              hipStream_t stream) {
    const float* x    = (const float*)d_in[0];
    const int*   ei   = (const int*)d_in[1];
    const float* W1   = (const float*)d_in[2];
    const float* b1   = (const float*)d_in[3];
    const float* W2   = (const float*)d_in[4];
    const float* b2   = (const float*)d_in[5];
    const float* Wlin = (const float*)d_in[6];
    const float* blin = (const float*)d_in[7];
    float* out = (float*)d_out;

    int N = in_sizes[0] / DIM;
    int E = in_sizes[1] / 2;
    const int* row = ei;
    const int* col = ei + E;

    int nscan = (N + SCHUNK - 1) / SCHUNK;   // 98 for N=100k (must be <= 256)

    // workspace layout
    int*   degi   = (int*)d_ws;                 // N
    int*   cursor = degi + N;                   // N
    int*   srcs   = cursor + N;                 // E
    int*   bsum   = srcs + E;                   // nscan (<=256)
    float* dinv   = (float*)(bsum + 256);       // N
    float* g      = dinv + N;                   // 64
    float* buf1   = g + 64;                     // N*DIM
    float* buf2   = buf1 + (size_t)N * DIM;     // N*DIM

    int nblk = (N + 255) / 256;

    // CSR build (shared by both layers)
    k_zero<<<nblk, 256, 0, stream>>>(degi, g, N);
    k_hist<<<2048, 256, 0, stream>>>(col, degi, E);
    k_scan_up<<<nscan, SB, 0, stream>>>(degi, cursor, dinv, bsum, N);
    k_scan_mid<<<1, 256, 0, stream>>>(bsum, nscan);
    k_scan_down<<<nscan, SB, 0, stream>>>(cursor, bsum, N);
    k_reorder<<<2048, 256, 0, stream>>>(row, col, cursor, srcs, E);

    int gblk = (N + NPB - 1) / NPB;

    // layer 1: hs1 -> buf1; h (post-bias+leaky) -> buf2
    k_mm_scale<<<nblk, 256, 0, stream>>>(x, W1, dinv, buf1, N);
    k_gather<1><<<gblk, NPB * TPN, 0, stream>>>(buf1, cursor, srcs, dinv, b1, buf2, N);

    // layer 2: hs2 -> buf1; h2 (pre-bias; bias folded into k_final) -> buf2
    k_mm_scale<<<nblk, 256, 0, stream>>>(buf2, W2, dinv, buf1, N);
    k_gather<0><<<gblk, NPB * TPN, 0, stream>>>(buf1, cursor, srcs, dinv, b2, buf2, N);

    // global pool + final linear
    k_reduce<<<1024, 192, 0, stream>>>(buf2, g, N);
    k_final<<<1, 64, 0, stream>>>(g, b2, Wlin, blin, out, N);
}

// Round 4
// 305.670 us; speedup vs baseline: 25.9106x; 1.3303x over previous
//
#include <hip/hip_runtime.h>
#include <hip/hip_bf16.h>

#define DIM 48
#define CAP 48   // max in-degree capacity (Poisson(16): P(deg>48) ~ 1e-10)
#define GNPB 32  // nodes per gather block
#define GTPN 6   // threads per node (16B bf16x8 chunks)

// cnt = 0, g = 0
__global__ void k_zero(int* __restrict__ cnt, float* __restrict__ g, int n) {
    int i = blockIdx.x * blockDim.x + threadIdx.x;
    if (i < n) cnt[i] = 0;
    if (i < 64) g[i] = 0.0f;
}

// padded-bucket CSR: srcs[col*CAP + p] = row
__global__ void k_reorder(const int* __restrict__ row, const int* __restrict__ col,
                          int* __restrict__ cnt, int* __restrict__ srcs, int E) {
    int i = blockIdx.x * blockDim.x + threadIdx.x;
    int st = gridDim.x * blockDim.x;
    for (; i < E; i += st) {
        int c = col[i];
        int p = atomicAdd(&cnt[c], 1);
        if (p < CAP) srcs[(size_t)c * CAP + p] = row[i];
    }
}

// dinv[i] = 1/sqrt(indeg + 1)
__global__ void k_dinv(const int* __restrict__ cnt, float* __restrict__ dinv, int n) {
    int i = blockIdx.x * blockDim.x + threadIdx.x;
    if (i < n) dinv[i] = 1.0f / sqrtf((float)(cnt[i] + 1));
}

// round-to-nearest-even f32 -> bf16 pair packed into one uint (lo=a, hi=b)
__device__ inline unsigned int pack_bf2(float a, float b) {
    unsigned int ua = __float_as_uint(a);
    ua = (ua + 0x7fffu + ((ua >> 16) & 1u)) >> 16;
    unsigned int ub = __float_as_uint(b);
    ub = (ub + 0x7fffu + ((ub >> 16) & 1u)) & 0xffff0000u;
    return ua | ub;
}

// hs[i,:] = bf16( (in[i,:] @ W) * dinv[i] )
__global__ void k_mm_scale(const float* __restrict__ in, const float* __restrict__ W,
                           const float* __restrict__ dinv,
                           unsigned short* __restrict__ hs, int n) {
    __shared__ float Ws[DIM * DIM];
    for (int i = threadIdx.x; i < DIM * DIM; i += blockDim.x) Ws[i] = W[i];
    __syncthreads();
    int node = blockIdx.x * blockDim.x + threadIdx.x;
    if (node >= n) return;
    float xr[DIM];
    const float4* xp = (const float4*)(in + (size_t)node * DIM);
    #pragma unroll
    for (int j = 0; j < DIM / 4; ++j) {
        float4 v = xp[j];
        xr[j * 4 + 0] = v.x; xr[j * 4 + 1] = v.y;
        xr[j * 4 + 2] = v.z; xr[j * 4 + 3] = v.w;
    }
    float o[DIM];
    #pragma unroll
    for (int f = 0; f < DIM; ++f) o[f] = 0.0f;
    for (int k = 0; k < DIM; ++k) {
        float xv = xr[k];
        #pragma unroll
        for (int f = 0; f < DIM; ++f) o[f] = fmaf(xv, Ws[k * DIM + f], o[f]);
    }
    float d = dinv[node];
    uint4* hp = (uint4*)(hs + (size_t)node * DIM);
    #pragma unroll
    for (int j = 0; j < DIM / 8; ++j) {
        uint4 v;
        v.x = pack_bf2(o[j * 8 + 0] * d, o[j * 8 + 1] * d);
        v.y = pack_bf2(o[j * 8 + 2] * d, o[j * 8 + 3] * d);
        v.z = pack_bf2(o[j * 8 + 4] * d, o[j * 8 + 5] * d);
        v.w = pack_bf2(o[j * 8 + 6] * d, o[j * 8 + 7] * d);
        hp[j] = v;
    }
}

// acc[0..7] += bf16x8 in v (lo half of each word = even elem)
__device__ inline void bf8_acc(uint4 v, float* acc) {
    acc[0] += __uint_as_float(v.x << 16);
    acc[1] += __uint_as_float(v.x & 0xffff0000u);
    acc[2] += __uint_as_float(v.y << 16);
    acc[3] += __uint_as_float(v.y & 0xffff0000u);
    acc[4] += __uint_as_float(v.z << 16);
    acc[5] += __uint_as_float(v.z & 0xffff0000u);
    acc[6] += __uint_as_float(v.w << 16);
    acc[7] += __uint_as_float(v.w & 0xffff0000u);
}

// out[i,:] = act( dinv[i] * (hs[i,:] + sum_{src} hs[src,:]) [+ b] ), f32 out
template <int RELU>
__global__ void k_gather(const unsigned short* __restrict__ hs, const int* __restrict__ cnt,
                         const int* __restrict__ srcs, const float* __restrict__ dinv,
                         const float* __restrict__ b, float* __restrict__ out, int n) {
    int t = threadIdx.x;
    int local = t / GTPN;
    int c = t - local * GTPN;          // bf16x8 chunk 0..5
    int i = blockIdx.x * GNPB + local;
    if (i >= n) return;
    int deg = min(cnt[i], CAP);
    const int* sp = srcs + (size_t)i * CAP;
    float acc[8];
    #pragma unroll
    for (int k = 0; k < 8; ++k) acc[k] = 0.0f;
    bf8_acc(*(const uint4*)(hs + (size_t)i * DIM + c * 8), acc);   // self loop
    for (int j = 0; j < deg; ++j) {
        int src = sp[j];
        bf8_acc(*(const uint4*)(hs + (size_t)src * DIM + c * 8), acc);
    }
    float d = dinv[i];
    float o[8];
    if (RELU) {
        #pragma unroll
        for (int k = 0; k < 8; ++k) {
            float v = acc[k] * d + b[c * 8 + k];
            o[k] = (v >= 0.0f) ? v : 0.01f * v;
        }
    } else {
        #pragma unroll
        for (int k = 0; k < 8; ++k) o[k] = acc[k] * d;
    }
    float4* op = (float4*)(out + (size_t)i * DIM + c * 8);
    op[0] = make_float4(o[0], o[1], o[2], o[3]);
    op[1] = make_float4(o[4], o[5], o[6], o[7]);
}

// g[f] += column sums of acc
__global__ void k_reduce(const float* __restrict__ acc, float* g, int n) {
    __shared__ float sm[192];
    int f = threadIdx.x % DIM;
    int r = threadIdx.x / DIM;   // 0..3
    float s = 0.0f;
    for (int i = blockIdx.x * 4 + r; i < n; i += gridDim.x * 4)
        s += acc[(size_t)i * DIM + f];
    sm[threadIdx.x] = s;
    __syncthreads();
    if (threadIdx.x < DIM)
        atomicAdd(&g[f], sm[f] + sm[DIM + f] + sm[2 * DIM + f] + sm[3 * DIM + f]);
}

// out[k] = sum_f (g[f] + n*b2[f]) * Wlin[f,k] + blin[k]
__global__ void k_final(const float* __restrict__ g, const float* __restrict__ b2,
                        const float* __restrict__ Wlin, const float* __restrict__ blin,
                        float* __restrict__ out, int n) {
    int k = threadIdx.x;
    if (k < 2) {
        float s = blin[k];
        for (int f = 0; f < DIM; ++f)
            s += (g[f] + (float)n * b2[f]) * Wlin[f * 2 + k];
        out[k] = s;
    }
}

extern "C" void kernel_launch(void* const* d_in, const int* in_sizes, int n_in,
                              void* d_out, int out_size, void* d_ws, size_t ws_size,
                              hipStream_t stream) {
    const float* x    = (const float*)d_in[0];
    const int*   ei   = (const int*)d_in[1];
    const float* W1   = (const float*)d_in[2];
    const float* b1   = (const float*)d_in[3];
    const float* W2   = (const float*)d_in[4];
    const float* b2   = (const float*)d_in[5];
    const float* Wlin = (const float*)d_in[6];
    const float* blin = (const float*)d_in[7];
    float* out = (float*)d_out;

    int N = in_sizes[0] / DIM;
    int E = in_sizes[1] / 2;
    const int* row = ei;
    const int* col = ei + E;

    // workspace layout (all 16B-aligned for N=100000)
    int*   cnt  = (int*)d_ws;                        // N
    float* dinv = (float*)(cnt + N);                 // N
    float* g    = dinv + N;                          // 64
    int*   srcs = (int*)(g + 64);                    // N*CAP  (19.2MB)
    unsigned short* hs = (unsigned short*)(srcs + (size_t)N * CAP);  // N*DIM bf16 (9.6MB)
    float* bufh = (float*)(hs + (size_t)N * DIM);    // N*DIM f32 (19.2MB)

    int nblk = (N + 255) / 256;
    int gblk = (N + GNPB - 1) / GNPB;

    // CSR build (padded buckets; shared by both layers)
    k_zero<<<nblk, 256, 0, stream>>>(cnt, g, N);
    k_reorder<<<2048, 256, 0, stream>>>(row, col, cnt, srcs, E);
    k_dinv<<<nblk, 256, 0, stream>>>(cnt, dinv, N);

    // layer 1
    k_mm_scale<<<nblk, 256, 0, stream>>>(x, W1, dinv, hs, N);
    k_gather<1><<<gblk, GNPB * GTPN, 0, stream>>>(hs, cnt, srcs, dinv, b1, bufh, N);

    // layer 2 (bias folded into k_final)
    k_mm_scale<<<nblk, 256, 0, stream>>>(bufh, W2, dinv, hs, N);
    k_gather<0><<<gblk, GNPB * GTPN, 0, stream>>>(hs, cnt, srcs, dinv, b2, bufh, N);

    // global pool + final linear
    k_reduce<<<1024, 192, 0, stream>>>(bufh, g, N);
    k_final<<<1, 64, 0, stream>>>(g, b2, Wlin, blin, out, N);
}

// Round 5
// 224.866 us; speedup vs baseline: 35.2214x; 1.3593x over previous
//
#include <hip/hip_runtime.h>
#include <hip/hip_bf16.h>

#define DIM 48
#define GNPB 32      // nodes per gather block
#define GTPN 6       // threads per node (16B bf16x8 chunks)

#define BKN 192      // nodes per coarse bucket
#define NB1MAX 544   // max bucket count supported (N <= 104448)
#define BCAPE 4608   // LDS staging capacity (edges) in partB; lambda=3072, +28 sigma

// bhist = 0, g = 0
__global__ void k_zero1(int* __restrict__ bhist, float* __restrict__ g, int nb1) {
    int i = blockIdx.x * blockDim.x + threadIdx.x;
    if (i < nb1) bhist[i] = 0;
    if (i < 64) g[i] = 0.0f;
}

// coarse bucket histogram (LDS-privatized)
__global__ void k_hist1(const int* __restrict__ col, int* __restrict__ bhist,
                        int E, int nb1) {
    __shared__ int h[NB1MAX];
    for (int i = threadIdx.x; i < nb1; i += blockDim.x) h[i] = 0;
    __syncthreads();
    int i0 = blockIdx.x * blockDim.x + threadIdx.x;
    int st = gridDim.x * blockDim.x;
    for (int e = i0; e < E; e += st) atomicAdd(&h[col[e] / BKN], 1);
    __syncthreads();
    for (int i = threadIdx.x; i < nb1; i += blockDim.x)
        if (h[i]) atomicAdd(&bhist[i], h[i]);
}

// exclusive scan of bhist -> bstart[0..nb1], bcursor = bstart. 1 block, 1024 thr.
__global__ void k_scan1(const int* __restrict__ bhist, int* __restrict__ bstart,
                        int* __restrict__ bcursor, int nb1, int E) {
    __shared__ int sm[1024];
    int t = threadIdx.x;
    sm[t] = (t < nb1) ? bhist[t] : 0;
    __syncthreads();
    for (int off = 1; off < 1024; off <<= 1) {
        int v = (t >= off) ? sm[t - off] : 0;
        __syncthreads();
        sm[t] += v;
        __syncthreads();
    }
    if (t < nb1) {
        int ex = (t == 0) ? 0 : sm[t - 1];
        bstart[t] = ex;
        bcursor[t] = ex;
    }
    if (t == nb1 - 1) bstart[nb1] = sm[t];   // == E
}

// partition edges into coarse buckets: part[pos] = (col, row)
__global__ void k_partA(const int* __restrict__ row, const int* __restrict__ col,
                        int* bcursor, uint2* __restrict__ part, int E, int nb1) {
    __shared__ int hist[NB1MAX];
    __shared__ int base[NB1MAX];
    __shared__ int lcur[NB1MAX];
    int chunk = (E + gridDim.x - 1) / gridDim.x;
    int lo = blockIdx.x * chunk;
    int hi = min(lo + chunk, E);
    for (int i = threadIdx.x; i < nb1; i += blockDim.x) { hist[i] = 0; lcur[i] = 0; }
    __syncthreads();
    for (int e = lo + threadIdx.x; e < hi; e += blockDim.x)
        atomicAdd(&hist[col[e] / BKN], 1);
    __syncthreads();
    for (int i = threadIdx.x; i < nb1; i += blockDim.x)
        if (hist[i]) base[i] = atomicAdd(&bcursor[i], hist[i]);
    __syncthreads();
    for (int e = lo + threadIdx.x; e < hi; e += blockDim.x) {
        int c = col[e];
        int b = c / BKN;
        int s = atomicAdd(&lcur[b], 1);
        part[base[b] + s] = make_uint2((unsigned)c, (unsigned)row[e]);
    }
}

// per-bucket counting sort -> exact CSR srcs/nodeoff; also dinv.
__global__ void k_partB(const uint2* __restrict__ part, const int* __restrict__ bstart,
                        int* __restrict__ nodeoff, float* __restrict__ dinv,
                        int* __restrict__ srcs, int N, int E, int nb1) {
    __shared__ int cnt[BKN];
    __shared__ int cur[BKN];
    __shared__ int sc[256];
    __shared__ int outb[BCAPE];
    int b = blockIdx.x;
    int nlo = b * BKN;
    int elo = bstart[b];
    int ehi = bstart[b + 1];
    int nE = ehi - elo;
    int t = threadIdx.x;
    if (t < BKN) cnt[t] = 0;
    __syncthreads();
    for (int e = elo + t; e < ehi; e += blockDim.x)
        atomicAdd(&cnt[part[e].x - nlo], 1);
    __syncthreads();
    int v = (t < BKN) ? cnt[t] : 0;
    sc[t] = v;
    __syncthreads();
    for (int off = 1; off < 256; off <<= 1) {
        int u = (t >= off) ? sc[t - off] : 0;
        __syncthreads();
        sc[t] += u;
        __syncthreads();
    }
    int ex = (t == 0) ? 0 : sc[t - 1];
    if (t < BKN && nlo + t < N) {
        nodeoff[nlo + t] = elo + ex;
        dinv[nlo + t] = 1.0f / sqrtf((float)(v + 1));
        cur[t] = ex;
    }
    if (b == nb1 - 1 && t == 0) nodeoff[N] = E;
    __syncthreads();
    if (nE <= BCAPE) {
        for (int e = elo + t; e < ehi; e += blockDim.x) {
            uint2 p = part[e];
            int s = atomicAdd(&cur[p.x - nlo], 1);
            outb[s] = (int)p.y;
        }
        __syncthreads();
        for (int i = t; i < nE; i += blockDim.x) srcs[elo + i] = outb[i];
    } else {  // overflow fallback (statistically unreachable)
        for (int e = elo + t; e < ehi; e += blockDim.x) {
            uint2 p = part[e];
            int s = atomicAdd(&cur[p.x - nlo], 1);
            srcs[elo + s] = (int)p.y;
        }
    }
}

// round-to-nearest-even f32 -> bf16 pair packed into one uint (lo=a, hi=b)
__device__ inline unsigned int pack_bf2(float a, float b) {
    unsigned int ua = __float_as_uint(a);
    ua = (ua + 0x7fffu + ((ua >> 16) & 1u)) >> 16;
    unsigned int ub = __float_as_uint(b);
    ub = (ub + 0x7fffu + ((ub >> 16) & 1u)) & 0xffff0000u;
    return ua | ub;
}

// hs[i,:] = bf16( (in[i,:] @ W) * dinv[i] )
__global__ void k_mm_scale(const float* __restrict__ in, const float* __restrict__ W,
                           const float* __restrict__ dinv,
                           unsigned short* __restrict__ hs, int n) {
    __shared__ float Ws[DIM * DIM];
    for (int i = threadIdx.x; i < DIM * DIM; i += blockDim.x) Ws[i] = W[i];
    __syncthreads();
    int node = blockIdx.x * blockDim.x + threadIdx.x;
    if (node >= n) return;
    float xr[DIM];
    const float4* xp = (const float4*)(in + (size_t)node * DIM);
    #pragma unroll
    for (int j = 0; j < DIM / 4; ++j) {
        float4 v = xp[j];
        xr[j * 4 + 0] = v.x; xr[j * 4 + 1] = v.y;
        xr[j * 4 + 2] = v.z; xr[j * 4 + 3] = v.w;
    }
    float o[DIM];
    #pragma unroll
    for (int f = 0; f < DIM; ++f) o[f] = 0.0f;
    for (int k = 0; k < DIM; ++k) {
        float xv = xr[k];
        #pragma unroll
        for (int f = 0; f < DIM; ++f) o[f] = fmaf(xv, Ws[k * DIM + f], o[f]);
    }
    float d = dinv[node];
    uint4* hp = (uint4*)(hs + (size_t)node * DIM);
    #pragma unroll
    for (int j = 0; j < DIM / 8; ++j) {
        uint4 v;
        v.x = pack_bf2(o[j * 8 + 0] * d, o[j * 8 + 1] * d);
        v.y = pack_bf2(o[j * 8 + 2] * d, o[j * 8 + 3] * d);
        v.z = pack_bf2(o[j * 8 + 4] * d, o[j * 8 + 5] * d);
        v.w = pack_bf2(o[j * 8 + 6] * d, o[j * 8 + 7] * d);
        hp[j] = v;
    }
}

// acc[0..7] += bf16x8 in v
__device__ inline void bf8_acc(uint4 v, float* acc) {
    acc[0] += __uint_as_float(v.x << 16);
    acc[1] += __uint_as_float(v.x & 0xffff0000u);
    acc[2] += __uint_as_float(v.y << 16);
    acc[3] += __uint_as_float(v.y & 0xffff0000u);
    acc[4] += __uint_as_float(v.z << 16);
    acc[5] += __uint_as_float(v.z & 0xffff0000u);
    acc[6] += __uint_as_float(v.w << 16);
    acc[7] += __uint_as_float(v.w & 0xffff0000u);
}

// out[i,:] = act( dinv[i] * (hs[i,:] + sum_{src} hs[src,:]) [+ b] ), f32 out
template <int RELU>
__global__ void k_gather(const unsigned short* __restrict__ hs,
                         const int* __restrict__ nodeoff, const int* __restrict__ srcs,
                         const float* __restrict__ dinv, const float* __restrict__ b,
                         float* __restrict__ out, int n) {
    int t = threadIdx.x;
    int local = t / GTPN;
    int c = t - local * GTPN;          // bf16x8 chunk 0..5
    int i = blockIdx.x * GNPB + local;
    if (i >= n) return;
    int start = nodeoff[i];
    int end = nodeoff[i + 1];
    float acc[8];
    #pragma unroll
    for (int k = 0; k < 8; ++k) acc[k] = 0.0f;
    bf8_acc(*(const uint4*)(hs + (size_t)i * DIM + c * 8), acc);   // self loop
    for (int j = start; j < end; ++j) {
        int src = srcs[j];
        bf8_acc(*(const uint4*)(hs + (size_t)src * DIM + c * 8), acc);
    }
    float d = dinv[i];
    float o[8];
    if (RELU) {
        #pragma unroll
        for (int k = 0; k < 8; ++k) {
            float v = acc[k] * d + b[c * 8 + k];
            o[k] = (v >= 0.0f) ? v : 0.01f * v;
        }
    } else {
        #pragma unroll
        for (int k = 0; k < 8; ++k) o[k] = acc[k] * d;
    }
    float4* op = (float4*)(out + (size_t)i * DIM + c * 8);
    op[0] = make_float4(o[0], o[1], o[2], o[3]);
    op[1] = make_float4(o[4], o[5], o[6], o[7]);
}

// g[f] += column sums of acc
__global__ void k_reduce(const float* __restrict__ acc, float* g, int n) {
    __shared__ float sm[192];
    int f = threadIdx.x % DIM;
    int r = threadIdx.x / DIM;   // 0..3
    float s = 0.0f;
    for (int i = blockIdx.x * 4 + r; i < n; i += gridDim.x * 4)
        s += acc[(size_t)i * DIM + f];
    sm[threadIdx.x] = s;
    __syncthreads();
    if (threadIdx.x < DIM)
        atomicAdd(&g[f], sm[f] + sm[DIM + f] + sm[2 * DIM + f] + sm[3 * DIM + f]);
}

// out[k] = sum_f (g[f] + n*b2[f]) * Wlin[f,k] + blin[k]
__global__ void k_final(const float* __restrict__ g, const float* __restrict__ b2,
                        const float* __restrict__ Wlin, const float* __restrict__ blin,
                        float* __restrict__ out, int n) {
    int k = threadIdx.x;
    if (k < 2) {
        float s = blin[k];
        for (int f = 0; f < DIM; ++f)
            s += (g[f] + (float)n * b2[f]) * Wlin[f * 2 + k];
        out[k] = s;
    }
}

static inline char* alignup(char* p, size_t a) {
    return (char*)(((uintptr_t)p + a - 1) & ~(uintptr_t)(a - 1));
}

extern "C" void kernel_launch(void* const* d_in, const int* in_sizes, int n_in,
                              void* d_out, int out_size, void* d_ws, size_t ws_size,
                              hipStream_t stream) {
    const float* x    = (const float*)d_in[0];
    const int*   ei   = (const int*)d_in[1];
    const float* W1   = (const float*)d_in[2];
    const float* b1   = (const float*)d_in[3];
    const float* W2   = (const float*)d_in[4];
    const float* b2   = (const float*)d_in[5];
    const float* Wlin = (const float*)d_in[6];
    const float* blin = (const float*)d_in[7];
    float* out = (float*)d_out;

    int N = in_sizes[0] / DIM;
    int E = in_sizes[1] / 2;
    const int* row = ei;
    const int* col = ei + E;
    int nb1 = (N + BKN - 1) / BKN;   // 521 for N=100k (<= NB1MAX)

    // workspace layout (16B-aligned slices)
    char* p = (char*)d_ws;
    int* bhist = (int*)p;                 p = alignup(p + nb1 * 4, 16);
    int* bstart = (int*)p;                p = alignup(p + (nb1 + 1) * 4, 16);
    int* bcursor = (int*)p;               p = alignup(p + nb1 * 4, 16);
    int* nodeoff = (int*)p;               p = alignup(p + (size_t)(N + 1) * 4, 16);
    float* dinv = (float*)p;              p = alignup(p + (size_t)N * 4, 16);
    float* g = (float*)p;                 p = alignup(p + 64 * 4, 16);
    int* srcs = (int*)p;                  p = alignup(p + (size_t)E * 4, 16);
    unsigned short* hs = (unsigned short*)p; p = alignup(p + (size_t)N * DIM * 2, 16);
    float* bufh = (float*)p;              // N*DIM f32; part aliases this region
    uint2* part = (uint2*)p;              // E*8B <= N*DIM*4B for these sizes

    int nblk = (N + 255) / 256;
    int gblk = (N + GNPB - 1) / GNPB;

    // CSR build (two-level partition, shared by both layers)
    k_zero1<<<(nb1 + 255) / 256, 256, 0, stream>>>(bhist, g, nb1);
    k_hist1<<<256, 256, 0, stream>>>(col, bhist, E, nb1);
    k_scan1<<<1, 1024, 0, stream>>>(bhist, bstart, bcursor, nb1, E);
    k_partA<<<256, 256, 0, stream>>>(row, col, bcursor, part, E, nb1);
    k_partB<<<nb1, 256, 0, stream>>>(part, bstart, nodeoff, dinv, srcs, N, E, nb1);

    // layer 1 (part region is dead after partB; bufh reuses it)
    k_mm_scale<<<nblk, 256, 0, stream>>>(x, W1, dinv, hs, N);
    k_gather<1><<<gblk, GNPB * GTPN, 0, stream>>>(hs, nodeoff, srcs, dinv, b1, bufh, N);

    // layer 2 (bias folded into k_final)
    k_mm_scale<<<nblk, 256, 0, stream>>>(bufh, W2, dinv, hs, N);
    k_gather<0><<<gblk, GNPB * GTPN, 0, stream>>>(hs, nodeoff, srcs, dinv, b2, bufh, N);

    // global pool + final linear
    k_reduce<<<1024, 192, 0, stream>>>(bufh, g, N);
    k_final<<<1, 64, 0, stream>>>(g, b2, Wlin, blin, out, N);
}